// Round 1
// baseline (365.211 us; speedup 1.0000x reference)
//
#include <hip/hip_runtime.h>

// FeatNeighbourCorr: feats [B=8, C=128, H=256, W=256] fp32 -> out [B,8,H,W] fp32.
// out[b,k,h,w] = dot_k(h,w) * rsqrt(ssq(h,w)) * rsqrt(ssq(neighbor_k))
//
// One block = one (b,h) row, 2 waves x 64 lanes, 64 channels/wave.
// Lane owns 4 consecutive cols (float4). Per channel: 3 global_load_dwordx4
// (rows h-1,h,h+1) + 3 shfl_down (right neighbor's .x) + ~40 FMAs.
// Cross-lane boundary dot terms are accumulated by the LEFT lane and
// delivered with one shfl_up after the loop; reflect edges resolve by
// symmetry (see exchange section).
// DEPTH-4 register pipeline: 12 dwordx4 loads (192 B/lane) in flight,
// 3-channel lookahead -> ~1200 cyc latency tolerance at 4 waves/SIMD,
// enough to cover ~900 cyc HBM latency -> HBM-BW-bound.

#define BB 8
#define CC 128
#define HH 256
#define WW 256
#define CSPLIT 2
#define CPW (CC / CSPLIT)  // 64

#define DD(k, j) acc[12 + (k)*4 + (j)]

__global__ __launch_bounds__(128) void featcorr_kernel(
    const float* __restrict__ feats, float* __restrict__ out) {
  const int lane = threadIdx.x;  // 0..63
  const int wy = threadIdx.y;    // 0..1
  // XCD-strip swizzle: blocks round-robin XCDs; give each XCD a contiguous
  // 32-row strip so the 3-row windows of adjacent h hit the same L2.
  const int h = (blockIdx.x % 8) * (HH / 8) + (blockIdx.x / 8);
  const int b = blockIdx.y;

  const int hm = (h == 0) ? 1 : h - 1;
  const int hp = (h == HH - 1) ? HH - 2 : h + 1;

  const size_t HW = (size_t)HH * WW;
  const int col0 = lane * 4;

  const float* pT = feats + ((size_t)b * CC + wy * CPW) * HW + (size_t)hm * WW + col0;
  const float* pM = feats + ((size_t)b * CC + wy * CPW) * HW + (size_t)h * WW + col0;
  const float* pB = feats + ((size_t)b * CC + wy * CPW) * HW + (size_t)hp * WW + col0;

  float acc[44];
#pragma unroll
  for (int a = 0; a < 44; ++a) acc[a] = 0.f;

  auto compute = [&](const float4 t, const float4 m, const float4 bt) {
    const float rT = __shfl_down(t.x, 1);
    const float rM = __shfl_down(m.x, 1);
    const float rB = __shfl_down(bt.x, 1);
    // squared sums (rows hm / h / hp)
    acc[0] += t.x * t.x;  acc[1] += t.y * t.y;  acc[2] += t.z * t.z;  acc[3] += t.w * t.w;
    acc[4] += m.x * m.x;  acc[5] += m.y * m.y;  acc[6] += m.z * m.z;  acc[7] += m.w * m.w;
    acc[8] += bt.x * bt.x; acc[9] += bt.y * bt.y; acc[10] += bt.z * bt.z; acc[11] += bt.w * bt.w;
    // k0 (h-1, w)
    DD(0, 0) += m.x * t.x; DD(0, 1) += m.y * t.y; DD(0, 2) += m.z * t.z; DD(0, 3) += m.w * t.w;
    // k4 (h+1, w)
    DD(4, 0) += m.x * bt.x; DD(4, 1) += m.y * bt.y; DD(4, 2) += m.z * bt.z; DD(4, 3) += m.w * bt.w;
    // k1 (h-1, w-1): j=1..3 local; slot (1,0) = boundary term for right lane
    DD(1, 1) += m.y * t.x; DD(1, 2) += m.z * t.y; DD(1, 3) += m.w * t.z;
    DD(1, 0) += rM * t.w;
    // k2 (h, w-1): boundary term rM*m.w == k6 boundary m.w*rM -> merged into DD(6,3)
    DD(2, 1) += m.y * m.x; DD(2, 2) += m.z * m.y; DD(2, 3) += m.w * m.z;
    // k3 (h+1, w-1)
    DD(3, 1) += m.y * bt.x; DD(3, 2) += m.z * bt.y; DD(3, 3) += m.w * bt.z;
    DD(3, 0) += rM * bt.w;
    // k5 (h+1, w+1)
    DD(5, 0) += m.x * bt.y; DD(5, 1) += m.y * bt.z; DD(5, 2) += m.z * bt.w; DD(5, 3) += m.w * rB;
    // k6 (h, w+1); DD(6,3) doubles as the k2 boundary term for lane+1
    DD(6, 0) += m.x * m.y; DD(6, 1) += m.y * m.z; DD(6, 2) += m.z * m.w; DD(6, 3) += m.w * rM;
    // k7 (h-1, w+1)
    DD(7, 0) += m.x * t.y; DD(7, 1) += m.y * t.z; DD(7, 2) += m.z * t.w; DD(7, 3) += m.w * rT;
  };

#define LOADSTEP(T, M, Bv)        \
  T = *(const float4*)pT;         \
  M = *(const float4*)pM;         \
  Bv = *(const float4*)pB;        \
  pT += HW; pM += HW; pB += HW;

  // ---- depth-4 pipelined channel loop (64 channels/wave) ----
  float4 tA, mA, bA, tB, mB, bB, tC, mC, bC, tD, mD, bD;
  LOADSTEP(tA, mA, bA)   // ch 0
  LOADSTEP(tB, mB, bB)   // ch 1
  LOADSTEP(tC, mC, bC)   // ch 2

  for (int i = 0; i < CPW / 4 - 1; ++i) {  // computes ch 4i..4i+3
    LOADSTEP(tD, mD, bD) compute(tA, mA, bA);
    LOADSTEP(tA, mA, bA) compute(tB, mB, bB);
    LOADSTEP(tB, mB, bB) compute(tC, mC, bC);
    LOADSTEP(tC, mC, bC) compute(tD, mD, bD);
  }
  LOADSTEP(tD, mD, bD) compute(tA, mA, bA);  // load ch63, compute ch60
  compute(tB, mB, bB);
  compute(tC, mC, bC);
  compute(tD, mD, bD);

  // ---- cross-wave reduction (single LDS buffer, 11 KB) ----
  __shared__ float lds[44][64];
  if (wy == 1) {
#pragma unroll
    for (int a = 0; a < 44; ++a) lds[a][lane] = acc[a];
  }
  __syncthreads();

  if (wy == 0) {
#pragma unroll
    for (int a = 0; a < 44; ++a) acc[a] += lds[a][lane];

    // deliver left-lane boundary dots; reflect edges via symmetry
    const float g1 = __shfl_up(DD(1, 0), 1);
    const float g2 = __shfl_up(DD(6, 3), 1);  // merged k2 boundary
    const float g3 = __shfl_up(DD(3, 0), 1);
    DD(1, 0) = (lane == 0) ? DD(7, 0) : g1;
    DD(2, 0) = (lane == 0) ? DD(6, 0) : g2;
    DD(3, 0) = (lane == 0) ? DD(5, 0) : g3;
    if (lane == 63) {
      DD(5, 3) = DD(3, 3);
      DD(6, 3) = DD(2, 3);
      DD(7, 3) = DD(1, 3);
    }

    float it[4], im[4], ib[4];
#pragma unroll
    for (int j = 0; j < 4; ++j) {
      it[j] = rsqrtf(acc[j]);
      im[j] = rsqrtf(acc[4 + j]);
      ib[j] = rsqrtf(acc[8 + j]);
    }
    // neighbor inverse norms over cols [col0-1 .. col0+4]
    float IT[6], IM[6], IB[6];
    IT[1] = it[0]; IT[2] = it[1]; IT[3] = it[2]; IT[4] = it[3];
    IM[1] = im[0]; IM[2] = im[1]; IM[3] = im[2]; IM[4] = im[3];
    IB[1] = ib[0]; IB[2] = ib[1]; IB[3] = ib[2]; IB[4] = ib[3];
    const float tl = __shfl_up(it[3], 1), ml = __shfl_up(im[3], 1), bl = __shfl_up(ib[3], 1);
    const float tr = __shfl_down(it[0], 1), mr = __shfl_down(im[0], 1), br = __shfl_down(ib[0], 1);
    IT[0] = (lane == 0) ? it[1] : tl;
    IM[0] = (lane == 0) ? im[1] : ml;
    IB[0] = (lane == 0) ? ib[1] : bl;
    IT[5] = (lane == 63) ? it[2] : tr;
    IM[5] = (lane == 63) ? im[2] : mr;
    IB[5] = (lane == 63) ? ib[2] : br;

    float* obase = out + ((size_t)b * 8) * HW + (size_t)h * WW + col0;
#pragma unroll
    for (int k = 0; k < 8; ++k) {
      float v[4];
#pragma unroll
      for (int j = 0; j < 4; ++j) {
        float in;
        switch (k) {
          case 0: in = it[j];     break;  // (h-1, w)
          case 1: in = IT[j];     break;  // (h-1, w-1)
          case 2: in = IM[j];     break;  // (h,   w-1)
          case 3: in = IB[j];     break;  // (h+1, w-1)
          case 4: in = ib[j];     break;  // (h+1, w)
          case 5: in = IB[j + 2]; break;  // (h+1, w+1)
          case 6: in = IM[j + 2]; break;  // (h,   w+1)
          default: in = IT[j + 2]; break; // (h-1, w+1)
        }
        v[j] = DD(k, j) * im[j] * in;
      }
      float4 o;
      o.x = v[0]; o.y = v[1]; o.z = v[2]; o.w = v[3];
      *(float4*)(obase + (size_t)k * HW) = o;
    }
  }
}

extern "C" void kernel_launch(void* const* d_in, const int* in_sizes, int n_in,
                              void* d_out, int out_size, void* d_ws, size_t ws_size,
                              hipStream_t stream) {
  const float* feats = (const float*)d_in[0];
  float* out = (float*)d_out;
  dim3 block(64, CSPLIT, 1);
  dim3 grid(HH, BB, 1);
  featcorr_kernel<<<grid, block, 0, stream>>>(feats, out);
}